// Round 3
// baseline (150.504 us; speedup 1.0000x reference)
//
#include <hip/hip_runtime.h>
#include <stdint.h>

// Problem constants (match reference)
constexpr int B = 524288;
constexpr int L = 7;
constexpr int V = 40;                       // 40 floats = 10 float4 per row
constexpr int NROWS = B * L;                // 3,670,016
constexpr int ROWS_PER_TILE = 256;          // one row per thread per tile
constexpr int F4_PER_ROW = 10;
constexpr int F4_PER_TILE = ROWS_PER_TILE * F4_PER_ROW;  // 2560 (40 KiB)
constexpr int NTILES = NROWS / ROWS_PER_TILE;            // 14336 (exact)
constexpr int GRID = 1024;                  // 14336 / 1024 = 14 tiles/block exact;
                                            // 4 blocks/CU x 256 CU = all resident
// Letter-slot masks: bit l set => position l must be a Letter
constexpr int BRAZIL_MASK = 0x07;           // LLLDDDD
constexpr int MERC_MASK   = 0x17;           // LLLDLDD

// Token id classes: 0..3 special, 4..29 letters, 30..39 digits.
// argmax is first-occurrence: on exact ties special > letter > digit.

typedef __attribute__((address_space(3))) char lds_char;
typedef __attribute__((address_space(1))) char glob_char;

__global__ __launch_bounds__(256) void layout_penalty_fused(
    const float* __restrict__ logits,
    const int* __restrict__ is_merc,
    unsigned int* __restrict__ ctrl,      // ctrl[0]=count, ctrl[1]=ticket (zeroed per call)
    float* __restrict__ out)
{
    __shared__ float4 tile[F4_PER_TILE];    // exactly 40960 B -> 4 blocks/CU
    const int t = threadIdx.x;
    const int waveBase = t & ~63;           // wave-uniform LDS dest base

    unsigned int local = 0;

    for (int tileIdx = blockIdx.x; tileIdx < NTILES; tileIdx += GRID) {
        const size_t baseF4 = (size_t)tileIdx * F4_PER_TILE;

        // Stage 40 KiB: linear LDS layout == global order satisfies the
        // wave-uniform-dest + lane*16 rule of global_load_lds.
        #pragma unroll
        for (int j = 0; j < F4_PER_ROW; ++j) {
            const float4* gp = reinterpret_cast<const float4*>(logits)
                               + baseF4 + (size_t)(j * 256 + t);
            lds_char* lp = (lds_char*)((char*)tile + (size_t)(j * 256 + waveBase) * 16);
            __builtin_amdgcn_global_load_lds((const glob_char*)gp, lp, 16, 0, 0);
        }
        __syncthreads();   // compiler drains vmcnt before the barrier

        // Thread t owns row t of the tile.
        const float4* row = &tile[t * F4_PER_ROW];

        float4 v0 = row[0];                 // ids 0..3 special
        float m_sp = fmaxf(fmaxf(v0.x, v0.y), fmaxf(v0.z, v0.w));

        float m_le = -3.4e38f;              // ids 4..27
        #pragma unroll
        for (int k = 1; k <= 6; ++k) {
            float4 v = row[k];
            m_le = fmaxf(m_le, fmaxf(fmaxf(v.x, v.y), fmaxf(v.z, v.w)));
        }
        float4 v7 = row[7];                 // 28,29 letters; 30,31 digits
        m_le = fmaxf(m_le, fmaxf(v7.x, v7.y));
        float m_di = fmaxf(v7.z, v7.w);
        float4 v8 = row[8];
        float4 v9 = row[9];
        m_di = fmaxf(m_di, fmaxf(fmaxf(v8.x, v8.y), fmaxf(v8.z, v8.w)));
        m_di = fmaxf(m_di, fmaxf(fmaxf(v9.x, v9.y), fmaxf(v9.z, v9.w)));

        const bool pred_is_digit  = (m_di > m_sp) && (m_di > m_le);
        const bool pred_is_letter = (m_le > m_sp) && (m_le >= m_di);

        const int R = tileIdx * ROWS_PER_TILE + t;
        const int b = R / 7;
        const int l = R - b * 7;
        const int  mask  = (is_merc[b] > 0) ? MERC_MASK : BRAZIL_MASK;
        const bool lslot = (mask >> l) & 1;
        local += (unsigned int)(lslot ? pred_is_digit : pred_is_letter);

        __syncthreads();   // all reads done before next tile overwrites LDS
    }

    // Block reduction: wave shfl, then reuse tile LDS (tile reads all done).
    #pragma unroll
    for (int off = 32; off > 0; off >>= 1)
        local += __shfl_down(local, off);

    unsigned int* s = reinterpret_cast<unsigned int*>(tile);
    const int wid = t >> 6;
    if ((t & 63) == 0) s[wid] = local;
    __syncthreads();

    if (t == 0) {
        const unsigned int cnt = s[0] + s[1] + s[2] + s[3];
        atomicAdd(&ctrl[0], cnt);           // device-scope
        __threadfence();                    // count visible before ticket
        const unsigned int old = atomicAdd(&ctrl[1], 1u);
        if (old == GRID - 1) {
            // all blocks' count-adds precede their ticket-adds (fenced),
            // so the total is complete. Exact integer -> bit-deterministic.
            const unsigned int total = atomicAdd(&ctrl[0], 0u);
            *out = (float)total * 0x1p-18f;   // 2*total/B, B = 2^19
        }
    }
}

extern "C" void kernel_launch(void* const* d_in, const int* in_sizes, int n_in,
                              void* d_out, int out_size, void* d_ws, size_t ws_size,
                              hipStream_t stream) {
    const float* logits  = (const float*)d_in[0];
    const int*   is_merc = (const int*)d_in[1];
    float*       out     = (float*)d_out;
    unsigned int* ctrl   = (unsigned int*)d_ws;

    hipMemsetAsync(ctrl, 0, 2 * sizeof(unsigned int), stream);
    layout_penalty_fused<<<GRID, 256, 0, stream>>>(logits, is_merc, ctrl, out);
}

// Round 4
// 108.442 us; speedup vs baseline: 1.3879x; 1.3879x over previous
//
#include <hip/hip_runtime.h>
#include <stdint.h>

// Problem constants (match reference)
constexpr int B = 524288;
constexpr int L = 7;
constexpr int V = 40;                       // 40 floats = 10 float4 per row
constexpr int NROWS = B * L;                // 3,670,016
constexpr int ROWS_PER_TILE = 256;          // one row per thread per tile
constexpr int F4_PER_ROW = 10;
constexpr int F4_PER_TILE = ROWS_PER_TILE * F4_PER_ROW;  // 2560 (40 KiB)
constexpr int NTILES = NROWS / ROWS_PER_TILE;            // 14336 (exact)
constexpr int GRID = 2048;                  // 14336 / 2048 = 7 tiles/block exact;
                                            // 2x oversubscription (4 blocks/CU fit)
// Letter-slot masks: bit l set => position l must be a Letter
constexpr int BRAZIL_MASK = 0x07;           // LLLDDDD
constexpr int MERC_MASK   = 0x17;           // LLLDLDD

// Token id classes: 0..3 special, 4..29 letters, 30..39 digits.
// argmax is first-occurrence: on exact ties special > letter > digit.

typedef __attribute__((address_space(3))) char lds_char;
typedef __attribute__((address_space(1))) char glob_char;

__global__ __launch_bounds__(256) void layout_penalty_fused(
    const float* __restrict__ logits,
    const int* __restrict__ is_merc,
    unsigned long long* __restrict__ ctrl,  // packed: [63:32]=count, [31:0]=ticket
    float* __restrict__ out)
{
    __shared__ float4 tile[F4_PER_TILE];    // exactly 40960 B -> 4 blocks/CU
    const int t = threadIdx.x;
    const int waveBase = t & ~63;           // wave-uniform LDS dest base

    unsigned int local = 0;

    for (int tileIdx = blockIdx.x; tileIdx < NTILES; tileIdx += GRID) {
        const size_t baseF4 = (size_t)tileIdx * F4_PER_TILE;

        // Stage 40 KiB: linear LDS layout == global order satisfies the
        // wave-uniform-dest + lane*16 rule of global_load_lds.
        #pragma unroll
        for (int j = 0; j < F4_PER_ROW; ++j) {
            const float4* gp = reinterpret_cast<const float4*>(logits)
                               + baseF4 + (size_t)(j * 256 + t);
            lds_char* lp = (lds_char*)((char*)tile + (size_t)(j * 256 + waveBase) * 16);
            __builtin_amdgcn_global_load_lds((const glob_char*)gp, lp, 16, 0, 0);
        }
        __syncthreads();   // compiler drains vmcnt before the barrier

        // Thread t owns row t of the tile.
        const float4* row = &tile[t * F4_PER_ROW];

        float4 v0 = row[0];                 // ids 0..3 special
        float m_sp = fmaxf(fmaxf(v0.x, v0.y), fmaxf(v0.z, v0.w));

        float m_le = -3.4e38f;              // ids 4..27
        #pragma unroll
        for (int k = 1; k <= 6; ++k) {
            float4 v = row[k];
            m_le = fmaxf(m_le, fmaxf(fmaxf(v.x, v.y), fmaxf(v.z, v.w)));
        }
        float4 v7 = row[7];                 // 28,29 letters; 30,31 digits
        m_le = fmaxf(m_le, fmaxf(v7.x, v7.y));
        float m_di = fmaxf(v7.z, v7.w);
        float4 v8 = row[8];
        float4 v9 = row[9];
        m_di = fmaxf(m_di, fmaxf(fmaxf(v8.x, v8.y), fmaxf(v8.z, v8.w)));
        m_di = fmaxf(m_di, fmaxf(fmaxf(v9.x, v9.y), fmaxf(v9.z, v9.w)));

        const bool pred_is_digit  = (m_di > m_sp) && (m_di > m_le);
        const bool pred_is_letter = (m_le > m_sp) && (m_le >= m_di);

        const int R = tileIdx * ROWS_PER_TILE + t;
        const int b = R / 7;
        const int l = R - b * 7;
        const int  mask  = (is_merc[b] > 0) ? MERC_MASK : BRAZIL_MASK;
        const bool lslot = (mask >> l) & 1;
        local += (unsigned int)(lslot ? pred_is_digit : pred_is_letter);

        __syncthreads();   // all reads done before next tile overwrites LDS
    }

    // Block reduction: wave shfl, then reuse tile LDS (tile reads all done).
    #pragma unroll
    for (int off = 32; off > 0; off >>= 1)
        local += __shfl_down(local, off);

    unsigned int* s = reinterpret_cast<unsigned int*>(tile);
    const int wid = t >> 6;
    if ((t & 63) == 0) s[wid] = local;
    __syncthreads();

    if (t == 0) {
        const unsigned long long cnt = s[0] + s[1] + s[2] + s[3];
        // Single fence-free atomic: high 32 bits accumulate the violation
        // count, low 32 bits count finished blocks. cnt <= 1792 per block,
        // 2048 blocks -> neither field overflows into the other.
        const unsigned long long old =
            atomicAdd(ctrl, (cnt << 32) | 1ull);
        if ((unsigned int)old == GRID - 1) {   // last block to arrive
            const unsigned long long total = (old >> 32) + cnt;
            *out = (float)total * 0x1p-18f;    // 2*total/B, B = 2^19
        }
    }
}

extern "C" void kernel_launch(void* const* d_in, const int* in_sizes, int n_in,
                              void* d_out, int out_size, void* d_ws, size_t ws_size,
                              hipStream_t stream) {
    const float* logits  = (const float*)d_in[0];
    const int*   is_merc = (const int*)d_in[1];
    float*       out     = (float*)d_out;
    unsigned long long* ctrl = (unsigned long long*)d_ws;  // 8B, 8-aligned

    hipMemsetAsync(ctrl, 0, sizeof(unsigned long long), stream);
    layout_penalty_fused<<<GRID, 256, 0, stream>>>(logits, is_merc, ctrl, out);
}

// Round 5
// 104.863 us; speedup vs baseline: 1.4352x; 1.0341x over previous
//
#include <hip/hip_runtime.h>
#include <stdint.h>

// Problem constants (match reference)
constexpr int B = 524288;
constexpr int L = 7;
constexpr int V = 40;                       // 40 floats = 10 float4 per row
constexpr int NROWS = B * L;                // 3,670,016
constexpr int ROWS_PER_TILE = 256;          // one row per thread per tile
constexpr int F4_PER_ROW = 10;
constexpr int F4_PER_TILE = ROWS_PER_TILE * F4_PER_ROW;  // 2560 (40 KiB)
constexpr int NTILES = NROWS / ROWS_PER_TILE;            // 14336 (exact)
constexpr int GRID = 2048;                  // 14336 / 2048 = 7 tiles/block exact
// Letter-slot masks: bit l set => position l must be a Letter
constexpr int BRAZIL_MASK = 0x07;           // LLLDDDD
constexpr int MERC_MASK   = 0x17;           // LLLDLDD

// Token id classes: 0..3 special, 4..29 letters, 30..39 digits.
// argmax is first-occurrence: on exact ties special > letter > digit.

typedef __attribute__((address_space(3))) char lds_char;
typedef __attribute__((address_space(1))) char glob_char;

__global__ __launch_bounds__(256) void layout_penalty_count(
    const float* __restrict__ logits,
    const int* __restrict__ is_merc,
    unsigned int* __restrict__ block_counts)
{
    __shared__ float4 tile[F4_PER_TILE];    // exactly 40960 B -> 4 blocks/CU
    const int t = threadIdx.x;
    const int waveBase = t & ~63;           // wave-uniform

    unsigned int local = 0;

    for (int tileIdx = blockIdx.x; tileIdx < NTILES; tileIdx += GRID) {
        const size_t baseF4 = (size_t)tileIdx * F4_PER_TILE;

        // Stage 40 KiB: LDS layout linear == global order, so the
        // wave-uniform-dest + lane*16 rule of global_load_lds is satisfied.
        #pragma unroll
        for (int j = 0; j < F4_PER_ROW; ++j) {
            const float4* gp = reinterpret_cast<const float4*>(logits)
                               + baseF4 + (size_t)(j * 256 + t);
            lds_char* lp = (lds_char*)((char*)tile + (size_t)(j * 256 + waveBase) * 16);
            __builtin_amdgcn_global_load_lds((const glob_char*)gp, lp, 16, 0, 0);
        }
        __syncthreads();   // compiler drains vmcnt before the barrier

        // Thread t owns row t of the tile.
        const float4* row = &tile[t * F4_PER_ROW];

        float4 v0 = row[0];                 // ids 0..3 special
        float m_sp = fmaxf(fmaxf(v0.x, v0.y), fmaxf(v0.z, v0.w));

        float m_le = -3.4e38f;              // ids 4..27
        #pragma unroll
        for (int k = 1; k <= 6; ++k) {
            float4 v = row[k];
            m_le = fmaxf(m_le, fmaxf(fmaxf(v.x, v.y), fmaxf(v.z, v.w)));
        }
        float4 v7 = row[7];                 // 28,29 letters; 30,31 digits
        m_le = fmaxf(m_le, fmaxf(v7.x, v7.y));
        float m_di = fmaxf(v7.z, v7.w);
        float4 v8 = row[8];
        float4 v9 = row[9];
        m_di = fmaxf(m_di, fmaxf(fmaxf(v8.x, v8.y), fmaxf(v8.z, v8.w)));
        m_di = fmaxf(m_di, fmaxf(fmaxf(v9.x, v9.y), fmaxf(v9.z, v9.w)));

        const bool pred_is_digit  = (m_di > m_sp) && (m_di > m_le);
        const bool pred_is_letter = (m_le > m_sp) && (m_le >= m_di);

        const int R = tileIdx * ROWS_PER_TILE + t;
        const int b = R / 7;
        const int l = R - b * 7;
        const int  mask  = (is_merc[b] > 0) ? MERC_MASK : BRAZIL_MASK;
        const bool lslot = (mask >> l) & 1;
        local += (unsigned int)(lslot ? pred_is_digit : pred_is_letter);

        __syncthreads();   // all reads done before next tile overwrites LDS
    }

    // Block reduction: wave shfl, then reuse tile LDS (all tile reads done).
    #pragma unroll
    for (int off = 32; off > 0; off >>= 1)
        local += __shfl_down(local, off);

    unsigned int* s = reinterpret_cast<unsigned int*>(tile);
    const int wid = t >> 6;
    if ((t & 63) == 0) s[wid] = local;
    __syncthreads();
    if (t == 0)
        block_counts[blockIdx.x] = s[0] + s[1] + s[2] + s[3];
}

__global__ __launch_bounds__(256) void layout_penalty_finalize(
    const unsigned int* __restrict__ block_counts,
    float* __restrict__ out)
{
    unsigned int local = 0;
    for (int i = threadIdx.x; i < GRID; i += 256)
        local += block_counts[i];
    #pragma unroll
    for (int off = 32; off > 0; off >>= 1)
        local += __shfl_down(local, off);

    __shared__ unsigned int s[4];
    const int wid = threadIdx.x >> 6;
    if ((threadIdx.x & 63) == 0) s[wid] = local;
    __syncthreads();
    if (threadIdx.x == 0)
        *out = 2.0f * (float)(s[0] + s[1] + s[2] + s[3]) / (float)B;
}

extern "C" void kernel_launch(void* const* d_in, const int* in_sizes, int n_in,
                              void* d_out, int out_size, void* d_ws, size_t ws_size,
                              hipStream_t stream) {
    const float* logits  = (const float*)d_in[0];
    const int*   is_merc = (const int*)d_in[1];
    float*       out     = (float*)d_out;
    unsigned int* block_counts = (unsigned int*)d_ws;   // GRID entries, fully rewritten each call

    layout_penalty_count<<<GRID, 256, 0, stream>>>(logits, is_merc, block_counts);
    layout_penalty_finalize<<<1, 256, 0, stream>>>(block_counts, out);
}